// Round 16
// baseline (728.127 us; speedup 1.0000x reference)
//
#include <hip/hip_runtime.h>
#include <hip/hip_bf16.h>
#include <hip/hip_fp16.h>
#include <math.h>

// ---------------------------------------------------------------------------
// ChaosSSMCore: selective diag-SSM
//   B=128, T=2048, D=256, M = B*T = 262144
//   delta = softplus(x @ Wd^T); decay = exp(-delta*exp(log_a))
//   update = delta * sigmoid(x @ Ws^T) * (x @ Wi^T)
//   states = scan(decay, update);  y = states * silu(x @ Wg^T)
//   out = y @ Wo^T
// ---------------------------------------------------------------------------

typedef __attribute__((ext_vector_type(8))) short s16x8;
typedef __attribute__((ext_vector_type(4))) float f32x4;

#define D_DIM 256
#define T_DIM 2048
#define B_DIM 128
#define NCHUNK2 32               // half-chunks of 64 timesteps
#define CLEN 128                 // full chunk (scan_out tile)

__device__ __forceinline__ unsigned short f2bf(float f) {
    union { float f; unsigned int u; } v; v.f = f;
    unsigned int r = v.u + 0x7fffu + ((v.u >> 16) & 1u);   // RNE
    return (unsigned short)(r >> 16);
}
__device__ __forceinline__ float bf2f(unsigned short s) {
    union { unsigned int u; float f; } v; v.u = ((unsigned int)s) << 16;
    return v.f;
}
__device__ __forceinline__ void gload_lds16(const void* g, void* l) {
    __builtin_amdgcn_global_load_lds(
        (const __attribute__((address_space(1))) unsigned int*)g,
        (__attribute__((address_space(3))) unsigned int*)l, 16, 0, 0);
}

// --------------------------- prep: build Wcat + Wo + ea --------------------
// Wcat[1024][256] bf16, row = n*4 + w, w: 0=delta 1=select 2=in 3=gate.
// Wo slab at +4*65536 (plain [256][256]). ea = exp(log_a).
__global__ __launch_bounds__(256) void prep_kernel(
    const float* __restrict__ W_in, const float* __restrict__ W_select,
    const float* __restrict__ W_gate, const float* __restrict__ W_out,
    const float* __restrict__ W_delta, const float* __restrict__ log_a,
    unsigned short* __restrict__ Wb, float* __restrict__ ea)
{
    int i = blockIdx.x * 256 + threadIdx.x;
    if (i < 4 * 65536) {
        int row = i >> 8, k = i & 255;
        int n = row >> 2, w = row & 3;
        const float* src = (w == 0) ? W_delta : (w == 1) ? W_select
                         : (w == 2) ? W_in    : W_gate;
        Wb[i] = f2bf(src[n * 256 + k]);
    } else if (i < 5 * 65536) {
        Wb[i] = f2bf(W_out[i - 4 * 65536]);
    } else if (i < 5 * 65536 + 256) {
        int j = i - 5 * 65536;
        ea[j] = expf(log_a[j]);
    }
}

// --------------------------- xcast: x fp32 -> bf16 -------------------------
__global__ __launch_bounds__(256) void xcast_kernel(
    const float* __restrict__ x, unsigned short* __restrict__ xb)
{
    size_t i = ((size_t)blockIdx.x * 256 + threadIdx.x) * 8;
    float4 p0 = *(const float4*)(x + i);
    float4 p1 = *(const float4*)(x + i + 4);
    s16x8 a;
    a[0] = (short)f2bf(p0.x); a[1] = (short)f2bf(p0.y);
    a[2] = (short)f2bf(p0.z); a[3] = (short)f2bf(p0.w);
    a[4] = (short)f2bf(p1.x); a[5] = (short)f2bf(p1.y);
    a[6] = (short)f2bf(p1.z); a[7] = (short)f2bf(p1.w);
    *(s16x8*)(xb + i) = a;
}

// --------------------------- gemm_fused v8: one-barrier K-loop -------------
// Block = 128m x 128 Wcat-rows (32 n x 4 W), 4 waves 2x2, wave = 64m x 64W.
// W staged FULL-K in LDS once (64 KB, granule-XOR source, linear dest);
// ONE __syncthreads; then the K-loop (8 kk of K=32) is BARRIER-FREE:
//   A fragments direct from global xb (L1/L2 absorb 2-wave reuse),
//   W fragments via ds_read (row stride 512B, g^=(row&7): 2-way free),
//   both register double-buffered (named even/odd sets, static indices) so
//   phase-(kk+1) loads issue before phase-kk MFMAs -> ~1 phase of cover.
// Epilogue: LDS-transpose + in-reg butterfly scan + coalesced full-line
// stores (R15-verified), reusing the W region after one barrier.
__global__ __launch_bounds__(256, 2) void gemm_fused_kernel(
    const unsigned short* __restrict__ xb, const unsigned short* __restrict__ Wcat,
    const float* __restrict__ ea,
    __half2* __restrict__ du, unsigned short* __restrict__ gate,
    float* __restrict__ cA, float* __restrict__ cS)
{
    __shared__ char lds[65536];    // W full-K [0,64K); epilogue tiles [0,28K)
    int bid = blockIdx.x;
    int wg  = (bid & 7) * 2048 + (bid >> 3);   // XCD chunk swizzle (16384%8==0)
    int mt  = wg >> 3;                          // = b*16 + c (chunk of 128 t)
    int nt  = wg & 7;
    int mbase = mt * 128;
    int nb = nt * 128;                          // Wcat row base
    int tid = threadIdx.x, lane = tid & 63, wid = tid >> 6;
    int l16 = lane & 15, lk = lane >> 4;
    int wr = wid >> 1, wc = wid & 1;

    // ---- stage W full-K: 4096 granules of 16B, 16 per thread ----
    // LDS dest linear in e (lane*16 pattern); source granule pre-swizzled.
#pragma unroll
    for (int j = 0; j < 16; ++j) {
        int e = j * 256 + tid;
        int row = e >> 5, gsl = e & 31;
        int g = gsl ^ (row & 7);
        gload_lds16(Wcat + (size_t)(nb + row) * D_DIM + g * 8,
                    lds + e * 16);
    }

    const unsigned short* xrow =
        xb + (size_t)(mbase + wr * 64 + l16) * D_DIM + lk * 8;

    // preload even-phase A fragments (kk=0) while W staging is in flight
    s16x8 xfA[4], xfB[4], wfA[4], wfB[4];
#pragma unroll
    for (int mf = 0; mf < 4; ++mf)
        xfA[mf] = *(const s16x8*)(xrow + mf * 16 * D_DIM);

    __syncthreads();   // drains all vmcnt; W-LDS valid; only barrier pre-epilogue

    // hoisted W ds_read byte offsets (per nf; + kgranule*16 at use site)
    int wrow[4];
#pragma unroll
    for (int nf = 0; nf < 4; ++nf)
        wrow[nf] = (wc * 64 + nf * 16 + l16) * 512;
    int wsw = ((wc * 64 + l16) & 7);   // row&7 is nf-independent (nf*16 ≡ 0 mod 8)

    // preload even-phase W fragments (kk=0)
#pragma unroll
    for (int nf = 0; nf < 4; ++nf)
        wfA[nf] = *(const s16x8*)(lds + wrow[nf] + ((lk ^ wsw) * 16));

    f32x4 acc[4][4] = {};           // [mf][nf]

#pragma unroll
    for (int k2 = 0; k2 < 4; ++k2) {
        int kkO = 2 * k2 + 1;
        // issue odd-phase loads (consumed after even MFMAs)
#pragma unroll
        for (int mf = 0; mf < 4; ++mf)
            xfB[mf] = *(const s16x8*)(xrow + mf * 16 * D_DIM + kkO * 32);
#pragma unroll
        for (int nf = 0; nf < 4; ++nf)
            wfB[nf] = *(const s16x8*)(lds + wrow[nf] + (((kkO * 4 + lk) ^ wsw) * 16));
        // even-phase MFMAs
#pragma unroll
        for (int nf = 0; nf < 4; ++nf)
#pragma unroll
            for (int mf = 0; mf < 4; ++mf)
                acc[mf][nf] = __builtin_amdgcn_mfma_f32_16x16x32_bf16(
                    wfA[nf], xfA[mf], acc[mf][nf], 0, 0, 0);
        // issue next even-phase loads
        if (k2 < 3) {
            int kkE = 2 * k2 + 2;
#pragma unroll
            for (int mf = 0; mf < 4; ++mf)
                xfA[mf] = *(const s16x8*)(xrow + mf * 16 * D_DIM + kkE * 32);
#pragma unroll
            for (int nf = 0; nf < 4; ++nf)
                wfA[nf] = *(const s16x8*)(lds + wrow[nf] + (((kkE * 4 + lk) ^ wsw) * 16));
        }
        // odd-phase MFMAs
#pragma unroll
        for (int nf = 0; nf < 4; ++nf)
#pragma unroll
            for (int mf = 0; mf < 4; ++mf)
                acc[mf][nf] = __builtin_amdgcn_mfma_f32_16x16x32_bf16(
                    wfB[nf], xfB[mf], acc[mf][nf], 0, 0, 0);
    }
    __syncthreads();   // all W-LDS reads done; region reused for transpose

    // ---- epilogue: acc[mf][nf] = {z_delta, z_select, z_in, z_gate}(m,n) ----
    // write outputs into LDS transpose tiles + in-register butterfly scan.
#pragma unroll
    for (int nf = 0; nf < 4; ++nf) {
        int dl = wc * 16 + nf * 4 + lk;        // n offset within 32
        float ean = ea[nt * 32 + dl];
        float A[4], S[4];
#pragma unroll
        for (int mf = 0; mf < 4; ++mf) {
            int t = wr * 64 + mf * 16 + l16;
            float zd = acc[mf][nf][0];
            float zs = acc[mf][nf][1];
            float zi = acc[mf][nf][2];
            float zg = acc[mf][nf][3];
            float e = __expf(zd);
            float delta = (zd > 15.f) ? zd : __logf(1.f + e);
            float dec = __expf(-delta * ean);
            float sel = 1.f / (1.f + __expf(-zs));
            float upd = delta * sel * zi;
            float g   = zg / (1.f + __expf(-zg));   // silu
            *(__half2*)(lds + (t * 36 + dl) * 4) = __floats2half2_rn(dec, upd);
            *(unsigned short*)(lds + 18432 + t * 80 + dl * 2) = f2bf(g);
            A[mf] = dec;
            S[mf] = upd;
        }
        // 16-lane butterfly compose over l16 (t-order = l16 within mf-block)
#pragma unroll
        for (int d = 1; d < 16; d <<= 1) {
            bool upper = (l16 & d);
#pragma unroll
            for (int mf = 0; mf < 4; ++mf) {
                float Ap = __shfl_xor(A[mf], d, 64);
                float Sp = __shfl_xor(S[mf], d, 64);
                float Se = upper ? Sp : S[mf];
                float Al = upper ? A[mf] : Ap;
                float Sl = upper ? S[mf] : Sp;
                S[mf] = fmaf(Al, Se, Sl);
                A[mf] = A[mf] * Ap;
            }
        }
        // in-thread compose across mf (t ascending: mf-blocks of 16)
        float cAe = A[0], cSe = S[0];
#pragma unroll
        for (int mf = 1; mf < 4; ++mf) {
            cSe = fmaf(A[mf], cSe, S[mf]);
            cAe *= A[mf];
        }
        if (l16 == 0) {
            int hc = mt * 2 + wr;              // = b*32 + (c*2 + wr)
            cA[hc * D_DIM + nt * 32 + dl] = cAe;
            cS[hc * D_DIM + nt * 32 + dl] = cSe;
        }
    }
    __syncthreads();

    // ---- coalesced writeback: full-line stores ----
    // du: 128 rows x 32 half2 (128B/row) -> 8 x 16B lanes cover a full line
    {
        size_t dub = (size_t)mbase * D_DIM + nt * 32;
#pragma unroll
        for (int i = 0; i < 4; ++i) {
            int slot = i * 256 + tid;
            int t = slot >> 3, seg = slot & 7;
            f32x4 v = *(const f32x4*)(lds + t * 144 + seg * 16);
            *(f32x4*)(du + dub + (size_t)t * D_DIM + seg * 4) = v;
        }
        // gate: 128 rows x 32 u16 (64B/row); nt-sibling (same XCD) completes line
#pragma unroll
        for (int i = 0; i < 2; ++i) {
            int slot = i * 256 + tid;
            int t = slot >> 2, seg = slot & 3;
            f32x4 v = *(const f32x4*)(lds + 18432 + t * 80 + seg * 16);
            *(f32x4*)(gate + dub + (size_t)t * D_DIM + seg * 8) = v;
        }
    }
}

// --------------------------- scan pass 2: half-chunk carries ---------------
__global__ __launch_bounds__(256) void scan2_kernel(
    const float* __restrict__ cA, const float* __restrict__ cS,
    float* __restrict__ carry)
{
    int b = blockIdx.x;
    int d = threadIdx.x;
    float s = 0.f;
    for (int c = 0; c < NCHUNK2; ++c) {
        int idx = (b * NCHUNK2 + c) * D_DIM + d;
        carry[idx] = s;                 // state entering half-chunk c
        s = fmaf(cA[idx], s, cS[idx]);
    }
}

// --------------------------- fused scan3 + out-projection ------------------
// block = (b, chunk of 128): scans 128 t-rows (full D), builds y tile in LDS
// (bf16, chunk-XOR-swizzled), then computes out[128 x 256] = y @ Wo^T.
__global__ __launch_bounds__(256) void scan_out_kernel(
    const __half2* __restrict__ du, const unsigned short* __restrict__ gate,
    const float* __restrict__ carry, const unsigned short* __restrict__ Wo,
    float* __restrict__ out)
{
    __shared__ unsigned short yls[128 * 256];   // 64 KB
    int b = blockIdx.x >> 4;
    int c = blockIdx.x & 15;
    int tid = threadIdx.x;

    // ---- phase 1: sequential scan, y -> LDS (swizzled 16B chunks) ----
    {
        int d = tid;
        size_t base = ((size_t)b * T_DIM + (size_t)c * CLEN) * D_DIM + d;
        float s = carry[(b * NCHUNK2 + c * 2) * D_DIM + d];
        int dlo = d & 7, dch = d >> 3;
#pragma unroll 4
        for (int t = 0; t < CLEN; ++t) {
            __half2 v = du[base + (size_t)t * D_DIM];
            float dc = __low2float(v);
            float up = __high2float(v);
            s = fmaf(dc, s, up);
            float g = bf2f(gate[base + (size_t)t * D_DIM]);
            int off = t * 256 + ((dch ^ (t & 7)) << 3) + dlo;
            yls[off] = f2bf(s * g);
        }
    }
    __syncthreads();

    // ---- phase 2: out-tile GEMM, A-frag = Wo rows (global), B-frag = y (LDS)
    int lane = tid & 63, wid = tid >> 6;
    int l16 = lane & 15;
    int lkc = lane >> 4;            // k-subgroup 0..3
    int m0 = (wid >> 1) * 64;
    size_t rbase = (size_t)b * T_DIM + (size_t)c * CLEN;
    int r0 = lkc * 4;

    for (int nblk = 0; nblk < 2; ++nblk) {
        int n0 = (wid & 1) * 64 + nblk * 128;
        f32x4 acc[4][4] = {};
        for (int ks = 0; ks < 8; ++ks) {
            int kb = ks * 32 + lkc * 8;
            s16x8 yf[4];
#pragma unroll
            for (int mf = 0; mf < 4; ++mf) {
                int row = m0 + mf * 16 + l16;
                int chunk = (ks * 4 + lkc) ^ (row & 7);
                yf[mf] = *(const s16x8*)&yls[row * 256 + chunk * 8];
            }
#pragma unroll
            for (int nf = 0; nf < 4; ++nf) {
                s16x8 wfr = *(const s16x8*)(Wo + (size_t)(n0 + nf * 16 + l16) * D_DIM + kb);
#pragma unroll
                for (int mf = 0; mf < 4; ++mf)
                    acc[mf][nf] = __builtin_amdgcn_mfma_f32_16x16x32_bf16(
                        wfr, yf[mf], acc[mf][nf], 0, 0, 0);
            }
        }
        // D col = lane&15 = y row; D rows = n (4 consecutive) -> float4 stores
#pragma unroll
        for (int mf = 0; mf < 4; ++mf) {
            size_t rowg = rbase + m0 + mf * 16 + l16;
#pragma unroll
            for (int nf = 0; nf < 4; ++nf) {
                int n = n0 + nf * 16 + r0;
                *(f32x4*)(out + rowg * D_DIM + n) = acc[mf][nf];
            }
        }
    }
}

// ---------------------------------------------------------------------------
extern "C" void kernel_launch(void* const* d_in, const int* in_sizes, int n_in,
                              void* d_out, int out_size, void* d_ws, size_t ws_size,
                              hipStream_t stream)
{
    const float* x        = (const float*)d_in[0];
    const float* W_in     = (const float*)d_in[1];
    const float* W_select = (const float*)d_in[2];
    const float* W_gate   = (const float*)d_in[3];
    const float* W_out    = (const float*)d_in[4];
    const float* W_delta  = (const float*)d_in[5];
    const float* log_a    = (const float*)d_in[6];
    float* out = (float*)d_out;

    char* ws = (char*)d_ws;
    const size_t MB = 1ull << 20;
    unsigned short* Wb    = (unsigned short*)(ws);               // 640 KB
    float*          ea    = (float*)(ws + 655360);               // 1 KB
    unsigned short* xb    = (unsigned short*)(ws + 1 * MB);      // 128 MB
    __half2*        du    = (__half2*)(ws + 129 * MB);           // 256 MB
    unsigned short* gate  = (unsigned short*)(ws + 385 * MB);    // 128 MB
    float*          cA    = (float*)(ws + 513 * MB);             // 4 MB
    float*          cS    = (float*)(ws + 517 * MB);             // 4 MB
    float*          carry = (float*)(ws + 521 * MB);             // 4 MB
    // total: 525 MB

    prep_kernel<<<1281, 256, 0, stream>>>(W_in, W_select, W_gate, W_out,
                                          W_delta, log_a, Wb, ea);
    xcast_kernel<<<32768, 256, 0, stream>>>(x, xb);
    gemm_fused_kernel<<<16384, 256, 0, stream>>>(xb, Wb, ea, du, gate, cA, cS);
    scan2_kernel<<<B_DIM, 256, 0, stream>>>(cA, cS, carry);
    scan_out_kernel<<<B_DIM * NCHUNK2 / 2, 256, 0, stream>>>(du, gate, carry,
                                                             Wb + 4 * 65536, out);
}

// Round 17
// 584.907 us; speedup vs baseline: 1.2449x; 1.2449x over previous
//
#include <hip/hip_runtime.h>
#include <hip/hip_bf16.h>
#include <hip/hip_fp16.h>
#include <math.h>

// ---------------------------------------------------------------------------
// ChaosSSMCore: selective diag-SSM
//   B=128, T=2048, D=256, M = B*T = 262144
//   delta = softplus(x @ Wd^T); decay = exp(-delta*exp(log_a))
//   update = delta * sigmoid(x @ Ws^T) * (x @ Wi^T)
//   states = scan(decay, update);  y = states * silu(x @ Wg^T)
//   out = y @ Wo^T
// ---------------------------------------------------------------------------

typedef __attribute__((ext_vector_type(8))) short s16x8;
typedef __attribute__((ext_vector_type(4))) float f32x4;

#define D_DIM 256
#define T_DIM 2048
#define B_DIM 128
#define NCHUNK2 32               // half-chunks of 64 timesteps
#define CLEN 128                 // full chunk (scan_out tile)
#define BK 64                    // GEMM K-step

__device__ __forceinline__ unsigned short f2bf(float f) {
    union { float f; unsigned int u; } v; v.f = f;
    unsigned int r = v.u + 0x7fffu + ((v.u >> 16) & 1u);   // RNE
    return (unsigned short)(r >> 16);
}
__device__ __forceinline__ float bf2f(unsigned short s) {
    union { unsigned int u; float f; } v; v.u = ((unsigned int)s) << 16;
    return v.f;
}
__device__ __forceinline__ void gload_lds16(const void* g, void* l) {
    __builtin_amdgcn_global_load_lds(
        (const __attribute__((address_space(1))) unsigned int*)g,
        (__attribute__((address_space(3))) unsigned int*)l, 16, 0, 0);
}

// --------------------------- prep: build Wcat + Wo + ea --------------------
// Wcat[1024][256] bf16, row = n*4 + w, w: 0=delta 1=select 2=in 3=gate.
// Wo slab at +4*65536 (plain [256][256]). ea = exp(log_a).
__global__ __launch_bounds__(256) void prep_kernel(
    const float* __restrict__ W_in, const float* __restrict__ W_select,
    const float* __restrict__ W_gate, const float* __restrict__ W_out,
    const float* __restrict__ W_delta, const float* __restrict__ log_a,
    unsigned short* __restrict__ Wb, float* __restrict__ ea)
{
    int i = blockIdx.x * 256 + threadIdx.x;
    if (i < 4 * 65536) {
        int row = i >> 8, k = i & 255;
        int n = row >> 2, w = row & 3;
        const float* src = (w == 0) ? W_delta : (w == 1) ? W_select
                         : (w == 2) ? W_in    : W_gate;
        Wb[i] = f2bf(src[n * 256 + k]);
    } else if (i < 5 * 65536) {
        Wb[i] = f2bf(W_out[i - 4 * 65536]);
    } else if (i < 5 * 65536 + 256) {
        int j = i - 5 * 65536;
        ea[j] = expf(log_a[j]);
    }
}

// --------------------------- xcast: x fp32 -> bf16 -------------------------
__global__ __launch_bounds__(256) void xcast_kernel(
    const float* __restrict__ x, unsigned short* __restrict__ xb)
{
    size_t i = ((size_t)blockIdx.x * 256 + threadIdx.x) * 8;
    float4 p0 = *(const float4*)(x + i);
    float4 p1 = *(const float4*)(x + i + 4);
    s16x8 a;
    a[0] = (short)f2bf(p0.x); a[1] = (short)f2bf(p0.y);
    a[2] = (short)f2bf(p0.z); a[3] = (short)f2bf(p0.w);
    a[4] = (short)f2bf(p1.x); a[5] = (short)f2bf(p1.y);
    a[6] = (short)f2bf(p1.z); a[7] = (short)f2bf(p1.w);
    *(s16x8*)(xb + i) = a;
}

// --------------------------- gemm_fused v9 (R15 + conflict-free transpose) -
// K-loop identical to rounds 12/15 (best measured, 0 K-loop conflicts).
// Block = 128m x 128 Wcat-rows (32 n x 4 W), 4 waves 2x2 (wave 64x64).
// Epilogue LDS transpose now GRANULE-ROTATED: granule' = (granule + t) & 7
// for duT (and & 3 for gT) on both write and read sides. This removes the
// 8-way writeback-read conflict of round 15 (bank = 9t+4seg collided in
// 8-lane groups; rotated: exactly 2 lanes/bank = free).
//   duT: half2, row stride 36 words (144B)   [0, 18432)
//   gT : u16,   row stride 40 u16  ( 80B)    [18432, 28672)
// ea preloaded to registers before the K-loop. Fused scan1 unchanged.
__global__ __launch_bounds__(256, 3) void gemm_fused_kernel(
    const unsigned short* __restrict__ xb, const unsigned short* __restrict__ Wcat,
    const float* __restrict__ ea,
    __half2* __restrict__ du, unsigned short* __restrict__ gate,
    float* __restrict__ cA, float* __restrict__ cS)
{
    __shared__ char lds[32768];    // K-loop: A [0,16K), B [16K,32K); then tiles
    int bid = blockIdx.x;
    int wg  = (bid & 7) * 2048 + (bid >> 3);   // XCD chunk swizzle (16384%8==0)
    int mt  = wg >> 3;                          // = b*16 + c (chunk of 128 t)
    int nt  = wg & 7;
    int mbase = mt * 128;
    int nb = nt * 128;                          // Wcat row base
    int tid = threadIdx.x, lane = tid & 63, wid = tid >> 6;
    int l16 = lane & 15, lk = lane >> 4;
    int wr = wid >> 1, wc = wid & 1;
    int srow = tid >> 3;            // staging: 32 rows per issue-group
    int sgi  = tid & 7;             // staging granule (16B) within row

    // preload epilogue constants (off the epilogue critical path)
    float eav[4];
#pragma unroll
    for (int nf = 0; nf < 4; ++nf)
        eav[nf] = ea[nt * 32 + wc * 16 + nf * 4 + lk];

    f32x4 acc[4][4] = {};           // [mf][nf]

    for (int ks = 0; ks < 4; ++ks) {
        int kb = ks * BK;
        // ---- stage A (xb rows) and B (Wcat rows), pre-swizzled source ----
#pragma unroll
        for (int j = 0; j < 4; ++j) {
            int row = j * 32 + srow;
            int sg  = sgi ^ (row & 7);
            gload_lds16(xb + (size_t)(mbase + row) * D_DIM + kb + sg * 8,
                        lds + row * 128 + sgi * 16);
        }
#pragma unroll
        for (int j = 0; j < 4; ++j) {
            int row = j * 32 + srow;
            int sg  = sgi ^ (row & 7);
            gload_lds16(Wcat + (size_t)(nb + row) * D_DIM + kb + sg * 8,
                        lds + 16384 + row * 128 + sgi * 16);
        }
        __syncthreads();   // drains vmcnt -> staged data visible

        // ---- compute: 2 kk-halves, 8 ds_read + 16 MFMA each ----
#pragma unroll
        for (int kk = 0; kk < 2; ++kk) {
            int gp = ((kk * 4 + lk) ^ (l16 & 7)) * 16;   // swizzled granule
            s16x8 xf[4], wf[4];
#pragma unroll
            for (int mf = 0; mf < 4; ++mf)
                xf[mf] = *(const s16x8*)(lds
                           + (wr * 64 + mf * 16 + l16) * 128 + gp);
#pragma unroll
            for (int nf = 0; nf < 4; ++nf)
                wf[nf] = *(const s16x8*)(lds + 16384
                           + (wc * 64 + nf * 16 + l16) * 128 + gp);
#pragma unroll
            for (int nf = 0; nf < 4; ++nf)
#pragma unroll
                for (int mf = 0; mf < 4; ++mf)
                    acc[mf][nf] = __builtin_amdgcn_mfma_f32_16x16x32_bf16(
                        wf[nf], xf[mf], acc[mf][nf], 0, 0, 0);
        }
        __syncthreads();   // all reads done before next stage / LDS reuse
    }

    // ---- epilogue: acc[mf][nf] = {z_delta, z_select, z_in, z_gate}(m,n) ----
    // write outputs into rotated LDS transpose tiles + in-reg butterfly scan.
#pragma unroll
    for (int nf = 0; nf < 4; ++nf) {
        int dl = wc * 16 + nf * 4 + lk;        // n offset within 32
        float ean = eav[nf];
        int gdu = dl >> 2, odu = dl & 3;       // duT granule/offset
        int ggt = dl >> 3, ogt = dl & 7;       // gT granule/offset
        float A[4], S[4];
#pragma unroll
        for (int mf = 0; mf < 4; ++mf) {
            int t = wr * 64 + mf * 16 + l16;
            float zd = acc[mf][nf][0];
            float zs = acc[mf][nf][1];
            float zi = acc[mf][nf][2];
            float zg = acc[mf][nf][3];
            float e = __expf(zd);
            float delta = (zd > 15.f) ? zd : __logf(1.f + e);
            float dec = __expf(-delta * ean);
            float sel = 1.f / (1.f + __expf(-zs));
            float upd = delta * sel * zi;
            float g   = zg / (1.f + __expf(-zg));   // silu
            *(__half2*)(lds + t * 144 + ((gdu + t) & 7) * 16 + odu * 4) =
                __floats2half2_rn(dec, upd);
            *(unsigned short*)(lds + 18432 + t * 80 + ((ggt + t) & 3) * 16
                               + ogt * 2) = f2bf(g);
            A[mf] = dec;
            S[mf] = upd;
        }
        // 16-lane butterfly compose over l16 (t-order = l16 within mf-block)
#pragma unroll
        for (int d = 1; d < 16; d <<= 1) {
            bool upper = (l16 & d);
#pragma unroll
            for (int mf = 0; mf < 4; ++mf) {
                float Ap = __shfl_xor(A[mf], d, 64);
                float Sp = __shfl_xor(S[mf], d, 64);
                float Se = upper ? Sp : S[mf];
                float Al = upper ? A[mf] : Ap;
                float Sl = upper ? S[mf] : Sp;
                S[mf] = fmaf(Al, Se, Sl);
                A[mf] = A[mf] * Ap;
            }
        }
        // in-thread compose across mf (t ascending: mf-blocks of 16)
        float cAe = A[0], cSe = S[0];
#pragma unroll
        for (int mf = 1; mf < 4; ++mf) {
            cSe = fmaf(A[mf], cSe, S[mf]);
            cAe *= A[mf];
        }
        if (l16 == 0) {
            int hc = mt * 2 + wr;              // = b*32 + (c*2 + wr)
            cA[hc * D_DIM + nt * 32 + dl] = cAe;
            cS[hc * D_DIM + nt * 32 + dl] = cSe;
        }
    }
    __syncthreads();

    // ---- coalesced writeback: full-line stores (rotated granule reads) ----
    // du: 128 rows x 32 half2 (128B/row) -> 8 x 16B lanes cover a full line
    {
        size_t dub = (size_t)mbase * D_DIM + nt * 32;
#pragma unroll
        for (int i = 0; i < 4; ++i) {
            int slot = i * 256 + tid;
            int t = slot >> 3, seg = slot & 7;
            f32x4 v = *(const f32x4*)(lds + t * 144 + ((seg + t) & 7) * 16);
            *(f32x4*)(du + dub + (size_t)t * D_DIM + seg * 4) = v;
        }
        // gate: 128 rows x 32 u16 (64B/row); nt-sibling (same XCD) completes line
#pragma unroll
        for (int i = 0; i < 2; ++i) {
            int slot = i * 256 + tid;
            int t = slot >> 2, seg = slot & 3;
            f32x4 v = *(const f32x4*)(lds + 18432 + t * 80 + ((seg + t) & 3) * 16);
            *(f32x4*)(gate + dub + (size_t)t * D_DIM + seg * 8) = v;
        }
    }
}

// --------------------------- scan pass 2: half-chunk carries ---------------
__global__ __launch_bounds__(256) void scan2_kernel(
    const float* __restrict__ cA, const float* __restrict__ cS,
    float* __restrict__ carry)
{
    int b = blockIdx.x;
    int d = threadIdx.x;
    float s = 0.f;
    for (int c = 0; c < NCHUNK2; ++c) {
        int idx = (b * NCHUNK2 + c) * D_DIM + d;
        carry[idx] = s;                 // state entering half-chunk c
        s = fmaf(cA[idx], s, cS[idx]);
    }
}

// --------------------------- fused scan3 + out-projection ------------------
// block = (b, chunk of 128): scans 128 t-rows (full D), builds y tile in LDS
// (bf16, chunk-XOR-swizzled), then computes out[128 x 256] = y @ Wo^T.
__global__ __launch_bounds__(256) void scan_out_kernel(
    const __half2* __restrict__ du, const unsigned short* __restrict__ gate,
    const float* __restrict__ carry, const unsigned short* __restrict__ Wo,
    float* __restrict__ out)
{
    __shared__ unsigned short yls[128 * 256];   // 64 KB
    int b = blockIdx.x >> 4;
    int c = blockIdx.x & 15;
    int tid = threadIdx.x;

    // ---- phase 1: sequential scan, y -> LDS (swizzled 16B chunks) ----
    {
        int d = tid;
        size_t base = ((size_t)b * T_DIM + (size_t)c * CLEN) * D_DIM + d;
        float s = carry[(b * NCHUNK2 + c * 2) * D_DIM + d];
        int dlo = d & 7, dch = d >> 3;
#pragma unroll 4
        for (int t = 0; t < CLEN; ++t) {
            __half2 v = du[base + (size_t)t * D_DIM];
            float dc = __low2float(v);
            float up = __high2float(v);
            s = fmaf(dc, s, up);
            float g = bf2f(gate[base + (size_t)t * D_DIM]);
            int off = t * 256 + ((dch ^ (t & 7)) << 3) + dlo;
            yls[off] = f2bf(s * g);
        }
    }
    __syncthreads();

    // ---- phase 2: out-tile GEMM, A-frag = Wo rows (global), B-frag = y (LDS)
    int lane = tid & 63, wid = tid >> 6;
    int l16 = lane & 15;
    int lkc = lane >> 4;            // k-subgroup 0..3
    int m0 = (wid >> 1) * 64;
    size_t rbase = (size_t)b * T_DIM + (size_t)c * CLEN;
    int r0 = lkc * 4;

    for (int nblk = 0; nblk < 2; ++nblk) {
        int n0 = (wid & 1) * 64 + nblk * 128;
        f32x4 acc[4][4] = {};
        for (int ks = 0; ks < 8; ++ks) {
            int kb = ks * 32 + lkc * 8;
            s16x8 yf[4];
#pragma unroll
            for (int mf = 0; mf < 4; ++mf) {
                int row = m0 + mf * 16 + l16;
                int chunk = (ks * 4 + lkc) ^ (row & 7);
                yf[mf] = *(const s16x8*)&yls[row * 256 + chunk * 8];
            }
#pragma unroll
            for (int nf = 0; nf < 4; ++nf) {
                s16x8 wfr = *(const s16x8*)(Wo + (size_t)(n0 + nf * 16 + l16) * D_DIM + kb);
#pragma unroll
                for (int mf = 0; mf < 4; ++mf)
                    acc[mf][nf] = __builtin_amdgcn_mfma_f32_16x16x32_bf16(
                        wfr, yf[mf], acc[mf][nf], 0, 0, 0);
            }
        }
        // D col = lane&15 = y row; D rows = n (4 consecutive) -> float4 stores
#pragma unroll
        for (int mf = 0; mf < 4; ++mf) {
            size_t rowg = rbase + m0 + mf * 16 + l16;
#pragma unroll
            for (int nf = 0; nf < 4; ++nf) {
                int n = n0 + nf * 16 + r0;
                *(f32x4*)(out + rowg * D_DIM + n) = acc[mf][nf];
            }
        }
    }
}

// ---------------------------------------------------------------------------
extern "C" void kernel_launch(void* const* d_in, const int* in_sizes, int n_in,
                              void* d_out, int out_size, void* d_ws, size_t ws_size,
                              hipStream_t stream)
{
    const float* x        = (const float*)d_in[0];
    const float* W_in     = (const float*)d_in[1];
    const float* W_select = (const float*)d_in[2];
    const float* W_gate   = (const float*)d_in[3];
    const float* W_out    = (const float*)d_in[4];
    const float* W_delta  = (const float*)d_in[5];
    const float* log_a    = (const float*)d_in[6];
    float* out = (float*)d_out;

    char* ws = (char*)d_ws;
    const size_t MB = 1ull << 20;
    unsigned short* Wb    = (unsigned short*)(ws);               // 640 KB
    float*          ea    = (float*)(ws + 655360);               // 1 KB
    unsigned short* xb    = (unsigned short*)(ws + 1 * MB);      // 128 MB
    __half2*        du    = (__half2*)(ws + 129 * MB);           // 256 MB
    unsigned short* gate  = (unsigned short*)(ws + 385 * MB);    // 128 MB
    float*          cA    = (float*)(ws + 513 * MB);             // 4 MB
    float*          cS    = (float*)(ws + 517 * MB);             // 4 MB
    float*          carry = (float*)(ws + 521 * MB);             // 4 MB
    // total: 525 MB

    prep_kernel<<<1281, 256, 0, stream>>>(W_in, W_select, W_gate, W_out,
                                          W_delta, log_a, Wb, ea);
    xcast_kernel<<<32768, 256, 0, stream>>>(x, xb);
    gemm_fused_kernel<<<16384, 256, 0, stream>>>(xb, Wb, ea, du, gate, cA, cS);
    scan2_kernel<<<B_DIM, 256, 0, stream>>>(cA, cS, carry);
    scan_out_kernel<<<B_DIM * NCHUNK2 / 2, 256, 0, stream>>>(du, gate, carry,
                                                             Wb + 4 * 65536, out);
}